// Round 8
// baseline (665.873 us; speedup 1.0000x reference)
//
#include <hip/hip_runtime.h>

#define KCODES 16384
#define CDIM   32
#define NROWS  8192
#define RPB    32                 // rows per block
#define KT     128                // codes per loop iteration
#define KSPLIT 4                  // K-chunks
#define CHUNK  (KCODES/KSPLIT)    // 4096
#define TILES  (CHUNK/KT)         // 32

// workspace layout (float indices)
#define WS_MSE   0
#define WS_PLP   1
#define WS_AVGP  16                    // [16384]
#define WS_ENORM (16 + KCODES)         // [16384]
#define WS_PART  (16 + 2*KCODES)       // float4[KSPLIT][NROWS][2]

// output layout (floats): z_q [0, N*C), loss [N*C], idx [N*C+1, ...)
#define OUT_LOSS (NROWS*CDIM)
#define OUT_IDX  (NROWS*CDIM + 1)

__global__ __launch_bounds__(256) void prep_kernel(const float* __restrict__ emb,
                                                   float* __restrict__ ws) {
  int k = blockIdx.x * 256 + threadIdx.x;
  const float4* p = (const float4*)(emb + (size_t)k * CDIM);
  float s = 0.f;
#pragma unroll
  for (int i = 0; i < 8; ++i) {
    float4 v = p[i];
    s += v.x*v.x + v.y*v.y + v.z*v.z + v.w*v.w;
  }
  ws[WS_ENORM + k] = s;
}

// ---------------------------------------------------------------------------
// pass1: block = (rowgroup, chunk). 32 rows x 4096 codes; thread = 4 rows x
// 4 codes. Codebook fragments read DIRECTLY from global (L1/L2-resident,
// c4-double-buffered) — no LDS tile, NO barriers in the K-loop. z tile lives
// in LDS, re-read per tile as broadcast b128 (asm clobber blocks LICM hoist,
// keeping VGPR <= 128 for the 4-waves/SIMD tier; R7's zreg hoist -> 168 VGPR
// -> 2-wave tier was the occupancy cap). NO min-waves bound (R3/R5: spill).
// ---------------------------------------------------------------------------
__global__ __launch_bounds__(256) void pass1_part(const float* __restrict__ z,
                                                  const float* __restrict__ emb,
                                                  float* __restrict__ ws) {
  __shared__ float  zs[RPB][36];          // 4.6 KB, rows 144 B (16B-aligned)
  __shared__ float  znorm_s[RPB];
  __shared__ float2 dump[RPB*32*2];       // 16 KB top-2 dump

  const int tid   = threadIdx.x;
  const int n0    = blockIdx.x * RPB;
  const int kbase = blockIdx.y * CHUNK;
  const int b     = n0 >> 8;
  const int hw0   = n0 & 255;

  float4* part = (float4*)(ws + WS_PART);

  { // stage z tile: 32 rows x 32 ch (coalesced)
    int c  = tid >> 3;
    int i0 = (tid & 7) * 4;
    const float4 v = *(const float4*)(z + (size_t)b*8192 + c*256 + hw0 + i0);
    zs[i0+0][c] = v.x; zs[i0+1][c] = v.y; zs[i0+2][c] = v.z; zs[i0+3][c] = v.w;
  }
  __syncthreads();
  if (tid < RPB) {
    float t = 0.f;
#pragma unroll
    for (int c = 0; c < CDIM; ++c) t += zs[tid][c]*zs[tid][c];
    znorm_s[tid] = t;
  }
  __syncthreads();

  const int rg = tid >> 5;            // rows rg*4 .. rg*4+3
  const int cg = tid & 31;            // codes cg + 32*j

  float zn[4];
#pragma unroll
  for (int r = 0; r < 4; ++r) zn[r] = znorm_s[rg*4 + r];

  float t1l[4], t2l[4];
  int   t1c[4], t2c[4];
#pragma unroll
  for (int r = 0; r < 4; ++r) { t1l[r] = -3.0e38f; t2l[r] = -3.0e38f; t1c[r] = kbase; t2c[r] = kbase; }

  const float4* emb4  = (const float4*)emb;
  const float*  enorm = ws + WS_ENORM;
  const char*   zbase = (const char*)&zs[0][0];

  for (int t = 0; t < TILES; ++t) {
    const int k0 = kbase + t*KT;

    // per-tile fresh LDS offset; asm clobber prevents LICM from hoisting the
    // 32 zs reads out of the t-loop (which would recreate the 128-VGPR zreg)
    unsigned zoff = 0;
    asm volatile("" : "+v"(zoff));

    const float4* pj[4];
#pragma unroll
    for (int j = 0; j < 4; ++j) pj[j] = emb4 + (size_t)(k0 + cg + 32*j)*8;

    float en[4];
#pragma unroll
    for (int j = 0; j < 4; ++j) en[j] = enorm[k0 + cg + 32*j];

    float acc[4][4];
#pragma unroll
    for (int r = 0; r < 4; ++r)
#pragma unroll
      for (int j = 0; j < 4; ++j) acc[r][j] = 0.f;

    float4 ev[2][4];
#pragma unroll
    for (int j = 0; j < 4; ++j) ev[0][j] = pj[j][0];

#pragma unroll
    for (int c4 = 0; c4 < 8; ++c4) {
      const int cur = c4 & 1, nxt = cur ^ 1;
      if (c4 < 7) {
#pragma unroll
        for (int j = 0; j < 4; ++j) ev[nxt][j] = pj[j][c4 + 1];
      }
      float4 zv[4];
#pragma unroll
      for (int r = 0; r < 4; ++r)
        zv[r] = *(const float4*)(zbase + zoff + ((rg*4 + r)*36 + c4*4)*4);
#pragma unroll
      for (int j = 0; j < 4; ++j) {
#pragma unroll
        for (int r = 0; r < 4; ++r) {
          acc[r][j] = fmaf(zv[r].x, ev[cur][j].x, acc[r][j]);
          acc[r][j] = fmaf(zv[r].y, ev[cur][j].y, acc[r][j]);
          acc[r][j] = fmaf(zv[r].z, ev[cur][j].z, acc[r][j]);
          acc[r][j] = fmaf(zv[r].w, ev[cur][j].w, acc[r][j]);
        }
      }
    }

#pragma unroll
    for (int r = 0; r < 4; ++r) {
      float l[4];
#pragma unroll
      for (int j = 0; j < 4; ++j)
        l[j] = -100.f * fmaf(-2.f, acc[r][j], zn[r] + en[j]);   // same bits as R2/R7
      // branch-free sequential top-2 insert (codes ascending -> first-min ties)
#pragma unroll
      for (int j = 0; j < 4; ++j) {
        int   code = k0 + cg + 32*j;
        float lj   = l[j];
        bool  b1 = lj > t1l[r];
        bool  b2 = lj > t2l[r];
        float n2l = b1 ? t1l[r] : (b2 ? lj   : t2l[r]);
        int   n2c = b1 ? t1c[r] : (b2 ? code : t2c[r]);
        t1l[r] = b1 ? lj   : t1l[r];
        t1c[r] = b1 ? code : t1c[r];
        t2l[r] = n2l; t2c[r] = n2c;
      }
    }
  }

  // dump per-thread top-2 to LDS
#pragma unroll
  for (int r = 0; r < 4; ++r) {
    int row = rg*4 + r;
    dump[(row*32 + cg)*2 + 0] = make_float2(t1l[r], __int_as_float(t1c[r]));
    dump[(row*32 + cg)*2 + 1] = make_float2(t2l[r], __int_as_float(t2c[r]));
  }
  __syncthreads();

  if (tid < RPB) {  // one thread per row: exact top-4 of 64 pairs
    float bl0=-3.0e38f, bl1=-3.0e38f, bl2=-3.0e38f, bl3=-3.0e38f;
    int   bc0=0, bc1=0, bc2=0, bc3=0;
    const float2* dp = dump + (size_t)tid*64;
    for (int i = 0; i < 64; ++i) {
      float2 pr = dp[i];
      float pl = pr.x; int pc = __float_as_int(pr.y);
      if (pl > bl0 || (pl == bl0 && pc < bc0)) {
        bl3=bl2; bc3=bc2; bl2=bl1; bc2=bc1; bl1=bl0; bc1=bc0; bl0=pl; bc0=pc;
      } else if (pl > bl1 || (pl == bl1 && pc < bc1)) {
        bl3=bl2; bc3=bc2; bl2=bl1; bc2=bc1; bl1=pl; bc1=pc;
      } else if (pl > bl2 || (pl == bl2 && pc < bc2)) {
        bl3=bl2; bc3=bc2; bl2=pl; bc2=pc;
      } else if (pl > bl3 || (pl == bl3 && pc < bc3)) {
        bl3=pl; bc3=pc;
      }
    }
    size_t o = ((size_t)blockIdx.y*NROWS + n0 + tid)*2;
    part[o+0] = make_float4(bl0, __int_as_float(bc0), bl1, __int_as_float(bc1));
    part[o+1] = make_float4(bl2, __int_as_float(bc2), bl3, __int_as_float(bc3));
  }
}

// ---------------------------------------------------------------------------
// combine: per row, 16 pairs (top-4 x 4 chunks) -> idx (exact), lse, plp,
// avg_probs atomics. s includes the max pair's exp(0)=1 -> NaN-proof.
// ---------------------------------------------------------------------------
__global__ __launch_bounds__(256) void combine_kernel(float* __restrict__ ws,
                                                      float* __restrict__ out) {
  const float4* part = (const float4*)(ws + WS_PART);
  int n = blockIdx.x*256 + threadIdx.x;

  float l[16]; int c[16];
#pragma unroll
  for (int ch = 0; ch < KSPLIT; ++ch) {
    float4 a = part[((size_t)ch*NROWS + n)*2 + 0];
    float4 d = part[((size_t)ch*NROWS + n)*2 + 1];
    l[ch*4+0] = a.x; c[ch*4+0] = __float_as_int(a.y);
    l[ch*4+1] = a.z; c[ch*4+1] = __float_as_int(a.w);
    l[ch*4+2] = d.x; c[ch*4+2] = __float_as_int(d.y);
    l[ch*4+3] = d.z; c[ch*4+3] = __float_as_int(d.w);
  }
  float mm = l[0]; int ii = c[0];
#pragma unroll
  for (int i = 1; i < 16; ++i)
    if (l[i] > mm) { mm = l[i]; ii = c[i]; }
  out[OUT_IDX + n] = (float)ii;

  float s = 0.f;
#pragma unroll
  for (int i = 0; i < 16; ++i) s += __expf(l[i] - mm);   // includes exp(0)=1
  float lse = mm + __logf(s);

  float plp = 0.f;
#pragma unroll
  for (int i = 0; i < 16; ++i) {
    float u = l[i] - lse;
    float p = __expf(u);
    plp = fmaf(p, u, plp);
    if (p > 1e-12f) atomicAdd(&ws[WS_AVGP + c[i]], p);
  }
  for (int off = 1; off < 64; off <<= 1) plp += __shfl_xor(plp, off);
  if ((threadIdx.x & 63) == 0) atomicAdd(&ws[WS_PLP], plp);
}

// ---------------------------------------------------------------------------
// zq epilogue: straight-through output + MSE
// ---------------------------------------------------------------------------
__global__ __launch_bounds__(256) void zq_kernel(const float* __restrict__ z,
                                                 const float* __restrict__ emb,
                                                 float* __restrict__ ws,
                                                 float* __restrict__ out) {
  int f  = blockIdx.x*256 + threadIdx.x;   // f = b*8192 + c*256 + hw
  int hw = f & 255;
  int c  = (f >> 8) & 31;
  int b  = f >> 13;
  int n  = b*256 + hw;
  int idx = (int)out[OUT_IDX + n];
  float zq = emb[(size_t)idx*CDIM + c];
  float zf = z[f];
  out[f] = zf + (zq - zf);
  float d = zq - zf;
  float msel = d*d;
  for (int off = 1; off < 64; off <<= 1) msel += __shfl_xor(msel, off);
  if ((threadIdx.x & 63) == 0) atomicAdd(&ws[WS_MSE], msel);
}

__global__ __launch_bounds__(256) void finalize_kernel(const float* __restrict__ ws,
                                                       float* __restrict__ out) {
  __shared__ float red[256];
  float h = 0.f;
  for (int k = threadIdx.x; k < KCODES; k += 256) {
    float ap = ws[WS_AVGP + k] * (1.f/8192.f);
    h += ap * __logf(ap + 1e-5f);
  }
  red[threadIdx.x] = h;
  __syncthreads();
  for (int st = 128; st > 0; st >>= 1) {
    if (threadIdx.x < st) red[threadIdx.x] += red[threadIdx.x + st];
    __syncthreads();
  }
  if (threadIdx.x == 0) {
    float mse        = ws[WS_MSE] * (1.f/(8192.f*32.f));
    float sample_ent = -ws[WS_PLP] * (1.f/8192.f);
    out[OUT_LOSS] = 1.25f*mse + 0.1f*(sample_ent + red[0]);
  }
}

extern "C" void kernel_launch(void* const* d_in, const int* in_sizes, int n_in,
                              void* d_out, int out_size, void* d_ws, size_t ws_size,
                              hipStream_t stream) {
  (void)in_sizes; (void)n_in; (void)out_size; (void)ws_size;
  const float* z   = (const float*)d_in[0];
  const float* emb = (const float*)d_in[1];
  float* out = (float*)d_out;
  float* ws  = (float*)d_ws;

  // zero scalar accumulators + avg_probs
  hipMemsetAsync(ws, 0, (size_t)(16 + KCODES)*sizeof(float), stream);

  prep_kernel    <<<KCODES/256, 256, 0, stream>>>(emb, ws);
  pass1_part     <<<dim3(NROWS/RPB, KSPLIT), 256, 0, stream>>>(z, emb, ws);
  combine_kernel <<<NROWS/256, 256, 0, stream>>>(ws, out);
  zq_kernel      <<<(NROWS*CDIM)/256, 256, 0, stream>>>(z, emb, ws, out);
  finalize_kernel<<<1, 256, 0, stream>>>(ws, out);
}

// Round 9
// 470.007 us; speedup vs baseline: 1.4167x; 1.4167x over previous
//
#include <hip/hip_runtime.h>

#define KCODES 16384
#define CDIM   32
#define NROWS  8192
#define RPB    32                 // rows per block
#define KT     128                // codes per tile (double-buffered)
#define KSPLIT 4                  // K-chunks
#define CHUNK  (KCODES/KSPLIT)    // 4096
#define TILES  (CHUNK/KT)         // 32
#define ZREGC  3                  // c4 chunks of z in registers (48 VGPR); rest from LDS

// workspace layout (float indices)
#define WS_MSE   0
#define WS_PLP   1
#define WS_AVGP  16                    // [16384]
#define WS_ENORM (16 + KCODES)         // [16384]
#define WS_PART  (16 + 2*KCODES)       // float4[KSPLIT][NROWS][2]

// output layout (floats): z_q [0, N*C), loss [N*C], idx [N*C+1, ...)
#define OUT_LOSS (NROWS*CDIM)
#define OUT_IDX  (NROWS*CDIM + 1)

#define GLB_AS __attribute__((address_space(1)))
#define LDS_AS __attribute__((address_space(3)))

__global__ __launch_bounds__(256) void prep_kernel(const float* __restrict__ emb,
                                                   float* __restrict__ ws) {
  int k = blockIdx.x * 256 + threadIdx.x;
  const float4* p = (const float4*)(emb + (size_t)k * CDIM);
  float s = 0.f;
#pragma unroll
  for (int i = 0; i < 8; ++i) {
    float4 v = p[i];
    s += v.x*v.x + v.y*v.y + v.z*v.z + v.w*v.w;
  }
  ws[WS_ENORM + k] = s;
}

// ---------------------------------------------------------------------------
// pass1: block = (rowgroup, chunk). 32 rows x 4096 codes; thread = 4 rows x
// 4 codes. Codebook tile in LDS, TRANSPOSED [c4][code] (lane-stride-16B reads
// = conflict-free, and contiguous dest for global_load_lds DMA staging, which
// frees the R7 prefetch registers). z split: c4 0..2 in regs (48 VGPR), 3..7
// broadcast b128 from LDS per tile (asm clobber stops LICM re-hoist, R8-
// verified). Top-1/thread (argmin exact; loss terms via top-4/chunk, error
// <<{327.68 threshold}). Target VGPR<128 => 4 waves/SIMD tier; LDS 37 KB =>
// 4 blocks/CU. NO min-waves bound (R3/R5: forces spill, 9x).
// ---------------------------------------------------------------------------
__global__ __launch_bounds__(256) void pass1_part(const float* __restrict__ z,
                                                  const float* __restrict__ emb,
                                                  float* __restrict__ ws) {
  __shared__ float4 esT[2][8][KT];        // 32 KB, [buf][c4][code]
  __shared__ float  zs[RPB][36];          // 4.6 KB, rows 144 B (16B-aligned)
  __shared__ float  znorm_s[RPB];

  const int tid   = threadIdx.x;
  const int n0    = blockIdx.x * RPB;
  const int kbase = blockIdx.y * CHUNK;
  const int b     = n0 >> 8;
  const int hw0   = n0 & 255;

  float4* part = (float4*)(ws + WS_PART);
  const float4* emb4  = (const float4*)emb;
  const float*  enorm = ws + WS_ENORM;

  { // stage z tile: 32 rows x 32 ch (coalesced)
    int c  = tid >> 3;
    int i0 = (tid & 7) * 4;
    const float4 v = *(const float4*)(z + (size_t)b*8192 + c*256 + hw0 + i0);
    zs[i0+0][c] = v.x; zs[i0+1][c] = v.y; zs[i0+2][c] = v.z; zs[i0+3][c] = v.w;
  }
  // DMA tile 0 into buffer 0 (async; covered by the barrier below)
#pragma unroll
  for (int i = 0; i < 4; ++i) {
    int flat = i*256 + tid;
    int code = flat & 127, c4 = flat >> 7;
    const float4* g = emb4 + (size_t)(kbase + code)*8 + c4;
    float4* lb = &esT[0][0][0] + i*256 + (tid & 192);
    __builtin_amdgcn_global_load_lds((const GLB_AS void*)g, (LDS_AS void*)lb, 16, 0, 0);
  }
  __syncthreads();
  if (tid < RPB) {
    float t = 0.f;
#pragma unroll
    for (int c = 0; c < CDIM; ++c) t += zs[tid][c]*zs[tid][c];
    znorm_s[tid] = t;
  }
  __syncthreads();

  const int rg = tid >> 5;            // rows rg*4 .. rg*4+3
  const int cg = tid & 31;            // codes cg + 32*j

  float zn[4];
  float4 zreg[4][ZREGC];              // 48 VGPR: first 12 dims of each row
#pragma unroll
  for (int r = 0; r < 4; ++r) {
    zn[r] = znorm_s[rg*4 + r];
#pragma unroll
    for (int c4 = 0; c4 < ZREGC; ++c4)
      zreg[r][c4] = *(const float4*)(&zs[rg*4 + r][c4*4]);
  }

  float t1l[4]; int t1c[4];
#pragma unroll
  for (int r = 0; r < 4; ++r) { t1l[r] = -3.0e38f; t1c[r] = kbase; }

  const char* zbase = (const char*)&zs[0][0];

  for (int t = 0; t < TILES; ++t) {
    const int cur = t & 1, nxt = cur ^ 1;
    const int k0  = kbase + t*KT;

    // async DMA next tile into the other buffer (no VGPR round-trip)
    if (t + 1 < TILES) {
      const int k1 = k0 + KT;
#pragma unroll
      for (int i = 0; i < 4; ++i) {
        int flat = i*256 + tid;
        int code = flat & 127, c4 = flat >> 7;
        const float4* g = emb4 + (size_t)(k1 + code)*8 + c4;
        float4* lb = &esT[nxt][0][0] + i*256 + (tid & 192);
        __builtin_amdgcn_global_load_lds((const GLB_AS void*)g, (LDS_AS void*)lb, 16, 0, 0);
      }
    }

    float en[4];
#pragma unroll
    for (int j = 0; j < 4; ++j) en[j] = enorm[k0 + cg + 32*j];

    // fresh LDS offset per tile; blocks LICM from hoisting the zs reads
    unsigned zoff = 0;
    asm volatile("" : "+v"(zoff));

    float acc[4][4];
#pragma unroll
    for (int r = 0; r < 4; ++r)
#pragma unroll
      for (int j = 0; j < 4; ++j) acc[r][j] = 0.f;

#pragma unroll
    for (int c4 = 0; c4 < 8; ++c4) {
      float4 zv[4];
      if (c4 < ZREGC) {
#pragma unroll
        for (int r = 0; r < 4; ++r) zv[r] = zreg[r][c4];
      } else {
#pragma unroll
        for (int r = 0; r < 4; ++r)
          zv[r] = *(const float4*)(zbase + zoff + ((rg*4 + r)*36 + c4*4)*4);
      }
#pragma unroll
      for (int j = 0; j < 4; ++j) {
        float4 ev = esT[cur][c4][cg + 32*j];
#pragma unroll
        for (int r = 0; r < 4; ++r) {
          acc[r][j] = fmaf(zv[r].x, ev.x, acc[r][j]);
          acc[r][j] = fmaf(zv[r].y, ev.y, acc[r][j]);
          acc[r][j] = fmaf(zv[r].z, ev.z, acc[r][j]);
          acc[r][j] = fmaf(zv[r].w, ev.w, acc[r][j]);
        }
      }
    }

#pragma unroll
    for (int r = 0; r < 4; ++r) {
      float l[4];
#pragma unroll
      for (int j = 0; j < 4; ++j)
        l[j] = -100.f * fmaf(-2.f, acc[r][j], zn[r] + en[j]);   // same bits as R2..R8
      float lm = fmaxf(fmaxf(l[0], l[1]), fmaxf(l[2], l[3]));
      if (lm > t1l[r]) {
        int jstar = 3;                   // first j achieving max (ascending code)
        if (l[2] == lm) jstar = 2;
        if (l[1] == lm) jstar = 1;
        if (l[0] == lm) jstar = 0;
        t1c[r] = k0 + cg + 32*jstar;
        t1l[r] = lm;
      }
    }

    __syncthreads();   // DMA(t+1) done + all reads of cur done
  }

  // dump per-thread top-1 to LDS (alias onto esT; freed by final barrier)
  float2* dump = (float2*)&esT[0][0][0];  // 32 rows x 32 lanes = 8 KB
#pragma unroll
  for (int r = 0; r < 4; ++r)
    dump[(rg*4 + r)*32 + cg] = make_float2(t1l[r], __int_as_float(t1c[r]));
  __syncthreads();

  if (tid < RPB) {  // one thread per row: top-4 of the 32 lane-maxima
    float bl0=-3.0e38f, bl1=-3.0e38f, bl2=-3.0e38f, bl3=-3.0e38f;
    int   bc0=0, bc1=0, bc2=0, bc3=0;
    const float2* dp = dump + (size_t)tid*32;
    for (int i = 0; i < 32; ++i) {
      float2 pr = dp[i];
      float pl = pr.x; int pc = __float_as_int(pr.y);
      if (pl > bl0 || (pl == bl0 && pc < bc0)) {
        bl3=bl2; bc3=bc2; bl2=bl1; bc2=bc1; bl1=bl0; bc1=bc0; bl0=pl; bc0=pc;
      } else if (pl > bl1 || (pl == bl1 && pc < bc1)) {
        bl3=bl2; bc3=bc2; bl2=bl1; bc2=bc1; bl1=pl; bc1=pc;
      } else if (pl > bl2 || (pl == bl2 && pc < bc2)) {
        bl3=bl2; bc3=bc2; bl2=pl; bc2=pc;
      } else if (pl > bl3 || (pl == bl3 && pc < bc3)) {
        bl3=pl; bc3=pc;
      }
    }
    size_t o = ((size_t)blockIdx.y*NROWS + n0 + tid)*2;
    part[o+0] = make_float4(bl0, __int_as_float(bc0), bl1, __int_as_float(bc1));
    part[o+1] = make_float4(bl2, __int_as_float(bc2), bl3, __int_as_float(bc3));
  }
}

// ---------------------------------------------------------------------------
// combine: per row, 16 pairs (top-4 x 4 chunks) -> idx (exact), lse, plp,
// avg_probs atomics. s includes the max pair's exp(0)=1 -> NaN-proof.
// ---------------------------------------------------------------------------
__global__ __launch_bounds__(256) void combine_kernel(float* __restrict__ ws,
                                                      float* __restrict__ out) {
  const float4* part = (const float4*)(ws + WS_PART);
  int n = blockIdx.x*256 + threadIdx.x;

  float l[16]; int c[16];
#pragma unroll
  for (int ch = 0; ch < KSPLIT; ++ch) {
    float4 a = part[((size_t)ch*NROWS + n)*2 + 0];
    float4 d = part[((size_t)ch*NROWS + n)*2 + 1];
    l[ch*4+0] = a.x; c[ch*4+0] = __float_as_int(a.y);
    l[ch*4+1] = a.z; c[ch*4+1] = __float_as_int(a.w);
    l[ch*4+2] = d.x; c[ch*4+2] = __float_as_int(d.y);
    l[ch*4+3] = d.z; c[ch*4+3] = __float_as_int(d.w);
  }
  float mm = l[0]; int ii = c[0];
#pragma unroll
  for (int i = 1; i < 16; ++i)
    if (l[i] > mm) { mm = l[i]; ii = c[i]; }
  out[OUT_IDX + n] = (float)ii;

  float s = 0.f;
#pragma unroll
  for (int i = 0; i < 16; ++i) s += __expf(l[i] - mm);   // includes exp(0)=1
  float lse = mm + __logf(s);

  float plp = 0.f;
#pragma unroll
  for (int i = 0; i < 16; ++i) {
    float u = l[i] - lse;
    float p = __expf(u);
    plp = fmaf(p, u, plp);
    if (p > 1e-12f) atomicAdd(&ws[WS_AVGP + c[i]], p);
  }
  for (int off = 1; off < 64; off <<= 1) plp += __shfl_xor(plp, off);
  if ((threadIdx.x & 63) == 0) atomicAdd(&ws[WS_PLP], plp);
}

// ---------------------------------------------------------------------------
// zq epilogue: straight-through output + MSE
// ---------------------------------------------------------------------------
__global__ __launch_bounds__(256) void zq_kernel(const float* __restrict__ z,
                                                 const float* __restrict__ emb,
                                                 float* __restrict__ ws,
                                                 float* __restrict__ out) {
  int f  = blockIdx.x*256 + threadIdx.x;   // f = b*8192 + c*256 + hw
  int hw = f & 255;
  int c  = (f >> 8) & 31;
  int b  = f >> 13;
  int n  = b*256 + hw;
  int idx = (int)out[OUT_IDX + n];
  float zq = emb[(size_t)idx*CDIM + c];
  float zf = z[f];
  out[f] = zf + (zq - zf);
  float d = zq - zf;
  float msel = d*d;
  for (int off = 1; off < 64; off <<= 1) msel += __shfl_xor(msel, off);
  if ((threadIdx.x & 63) == 0) atomicAdd(&ws[WS_MSE], msel);
}

__global__ __launch_bounds__(256) void finalize_kernel(const float* __restrict__ ws,
                                                       float* __restrict__ out) {
  __shared__ float red[256];
  float h = 0.f;
  for (int k = threadIdx.x; k < KCODES; k += 256) {
    float ap = ws[WS_AVGP + k] * (1.f/8192.f);
    h += ap * __logf(ap + 1e-5f);
  }
  red[threadIdx.x] = h;
  __syncthreads();
  for (int st = 128; st > 0; st >>= 1) {
    if (threadIdx.x < st) red[threadIdx.x] += red[threadIdx.x + st];
    __syncthreads();
  }
  if (threadIdx.x == 0) {
    float mse        = ws[WS_MSE] * (1.f/(8192.f*32.f));
    float sample_ent = -ws[WS_PLP] * (1.f/8192.f);
    out[OUT_LOSS] = 1.25f*mse + 0.1f*(sample_ent + red[0]);
  }
}

extern "C" void kernel_launch(void* const* d_in, const int* in_sizes, int n_in,
                              void* d_out, int out_size, void* d_ws, size_t ws_size,
                              hipStream_t stream) {
  (void)in_sizes; (void)n_in; (void)out_size; (void)ws_size;
  const float* z   = (const float*)d_in[0];
  const float* emb = (const float*)d_in[1];
  float* out = (float*)d_out;
  float* ws  = (float*)d_ws;

  // zero scalar accumulators + avg_probs
  hipMemsetAsync(ws, 0, (size_t)(16 + KCODES)*sizeof(float), stream);

  prep_kernel    <<<KCODES/256, 256, 0, stream>>>(emb, ws);
  pass1_part     <<<dim3(NROWS/RPB, KSPLIT), 256, 0, stream>>>(z, emb, ws);
  combine_kernel <<<NROWS/256, 256, 0, stream>>>(ws, out);
  zq_kernel      <<<(NROWS*CDIM)/256, 256, 0, stream>>>(z, emb, ws, out);
  finalize_kernel<<<1, 256, 0, stream>>>(ws, out);
}

// Round 10
// 205.252 us; speedup vs baseline: 3.2442x; 2.2899x over previous
//
#include <hip/hip_runtime.h>

#define KCODES 16384
#define CDIM   32
#define NROWS  8192
#define KSPLIT 4                  // chunks (blockIdx.y)
#define CHUNK  (KCODES/KSPLIT)    // 4096
#define WCODES 1024               // codes per wave
#define NT     (WCODES/16)        // 64 MFMA code-tiles per wave
#define MARGIN 2.5f               // >3x worst-case f16 logit error (0.8)

typedef _Float16 half8 __attribute__((ext_vector_type(8)));
typedef float    floatx4 __attribute__((ext_vector_type(4)));

// workspace layout (float indices)
#define WS_MSE   0
#define WS_PLP   1
#define WS_AVGP  16                      // [16384]
#define WS_ENORM (16 + KCODES)           // [16384] fp32, exact
#define WS_ZNORM (16 + 2*KCODES)         // [8192]  fp32
#define WS_PART  (16 + 2*KCODES + NROWS) // float4[KSPLIT][NROWS]  (byte off %16==0)
#define WS_E16   (WS_PART + 4*KSPLIT*NROWS)      // f16[16384][32] = 262144 float-slots
#define WS_Z16   (WS_E16 + KCODES*16)            // f16[8192][32]  = 131072 float-slots
// total ~2.26 MB < R4-proven 3.67 MB

// output layout (floats): z_q [0, N*C), loss [N*C], idx [N*C+1, ...)
#define OUT_LOSS (NROWS*CDIM)
#define OUT_IDX  (NROWS*CDIM + 1)

// ---------------------------------------------------------------------------
// prep_e: enorm (exact fp32, same chain as prior rounds) + f16 conversion
// ---------------------------------------------------------------------------
__global__ __launch_bounds__(256) void prep_e(const float* __restrict__ emb,
                                              float* __restrict__ ws) {
  int k = blockIdx.x * 256 + threadIdx.x;
  const float4* p = (const float4*)(emb + (size_t)k * CDIM);
  _Float16* e16 = (_Float16*)(ws + WS_E16);
  float s = 0.f;
  half8 h[4];
#pragma unroll
  for (int i = 0; i < 8; ++i) {
    float4 v = p[i];
    s += v.x*v.x + v.y*v.y + v.z*v.z + v.w*v.w;
    h[i>>1][(i&1)*4+0] = (_Float16)v.x;
    h[i>>1][(i&1)*4+1] = (_Float16)v.y;
    h[i>>1][(i&1)*4+2] = (_Float16)v.z;
    h[i>>1][(i&1)*4+3] = (_Float16)v.w;
  }
  ws[WS_ENORM + k] = s;
  half8* dst = (half8*)(e16 + (size_t)k*32);
#pragma unroll
  for (int i = 0; i < 4; ++i) dst[i] = h[i];
}

// ---------------------------------------------------------------------------
// prep_z: znorm + f16 conversion; z[b][c][hw] reads are lane-coalesced
// ---------------------------------------------------------------------------
__global__ __launch_bounds__(256) void prep_z(const float* __restrict__ z,
                                              float* __restrict__ ws) {
  int b  = blockIdx.x;
  int t  = threadIdx.x;                 // hw
  int n  = b*256 + t;
  _Float16* z16 = (_Float16*)(ws + WS_Z16);
  float s = 0.f;
  half8 h[4];
#pragma unroll
  for (int c = 0; c < CDIM; ++c) {
    float v = z[(size_t)b*8192 + c*256 + t];
    s = fmaf(v, v, s);
    h[c>>3][c&7] = (_Float16)v;
  }
  ws[WS_ZNORM + n] = s;
  half8* dst = (half8*)(z16 + (size_t)n*32);
#pragma unroll
  for (int i = 0; i < 4; ++i) dst[i] = h[i];
}

// ---------------------------------------------------------------------------
// gemm_pass: block = (32 rows, chunk). 4 waves x 1024 codes. Per wave:
// 2 row-tiles x 64 code-tiles of v_mfma_f32_16x16x32_f16 (K=32 = full CDIM,
// one MFMA per 16x16 tile). A/B frags straight from global (L2-resident,
// 16B/lane, wave covers a contiguous 1KB). Epilogue: branchless top-2 of
// l' = dot - (zn+en)/2 per (row,lane-code-col). No barriers in the K-loop.
// Layouts per m89/m120: A[m=lane&15][k=quad*8+j], B[k][n=lane&15],
// C: col(n)=lane&15, row(m)=quad*4+reg.
// ---------------------------------------------------------------------------
__global__ __launch_bounds__(256) void gemm_pass(const float* __restrict__ ws_ro,
                                                 float* __restrict__ ws) {
  __shared__ float2 dmp1[64][33];       // [slot][row], pad 33 -> bank spread
  __shared__ float2 dmp2[64][33];
  __shared__ float4 d2[32][4];

  const int tid  = threadIdx.x;
  const int wv   = tid >> 6;
  const int lane = tid & 63;
  const int nn   = lane & 15;           // MFMA n / m index
  const int quad = lane >> 4;
  const int n0   = blockIdx.x * 32;
  const int kb   = blockIdx.y * CHUNK + wv * WCODES;

  const half8* z16v = (const half8*)(ws_ro + WS_Z16);
  const half8* e16v = (const half8*)(ws_ro + WS_E16);
  const float* enorm = ws_ro + WS_ENORM;
  const float* znorm = ws_ro + WS_ZNORM;
  float4* part = (float4*)(ws + WS_PART);

  // A-fragments: two row-tiles, loaded once
  half8 a0 = z16v[(size_t)(n0 + nn)*4 + quad];
  half8 a1 = z16v[(size_t)(n0 + 16 + nn)*4 + quad];

  float zn2[8];
#pragma unroll
  for (int i = 0; i < 8; ++i)           // i = T*4 + r -> row = T*16 + quad*4 + r
    zn2[i] = 0.5f * znorm[n0 + (i>>2)*16 + quad*4 + (i&3)];

  float t1l[8], t2l[8]; int t1c[8], t2c[8];
#pragma unroll
  for (int i = 0; i < 8; ++i) { t1l[i] = -3.0e38f; t2l[i] = -3.0e38f; t1c[i] = kb; t2c[i] = kb; }

  half8 bcur = e16v[(size_t)(kb + nn)*4 + quad];
  float en2c = 0.5f * enorm[kb + nn];
  int   codev = kb + nn;
  const floatx4 zero = {0.f, 0.f, 0.f, 0.f};

  for (int t = 0; t < NT; ++t) {
    const int tn = (t + 1 < NT) ? t + 1 : t;   // clamp: last prefetch reuses
    half8 bn   = e16v[(size_t)(kb + tn*16 + nn)*4 + quad];
    float en2n = 0.5f * enorm[kb + tn*16 + nn];

    floatx4 d0 = __builtin_amdgcn_mfma_f32_16x16x32_f16(a0, bcur, zero, 0, 0, 0);
    floatx4 d1 = __builtin_amdgcn_mfma_f32_16x16x32_f16(a1, bcur, zero, 0, 0, 0);

#pragma unroll
    for (int i = 0; i < 8; ++i) {
      float dot = (i < 4) ? d0[i & 3] : d1[i & 3];
      float lp  = dot - (zn2[i] + en2c);       // = -d/2 (unscaled logit)
      bool g1 = lp > t1l[i];
      bool g2 = lp > t2l[i];
      t2l[i] = g1 ? t1l[i] : (g2 ? lp    : t2l[i]);
      t2c[i] = g1 ? t1c[i] : (g2 ? codev : t2c[i]);
      t1l[i] = g1 ? lp    : t1l[i];
      t1c[i] = g1 ? codev : t1c[i];
    }
    bcur = bn; en2c = en2n; codev += 16;
  }

  // dump per-(lane,row) top-2, scaled to true logits l = 200*lp
  const int slot = wv*16 + nn;
#pragma unroll
  for (int i = 0; i < 8; ++i) {
    int row = (i>>2)*16 + quad*4 + (i&3);
    dmp1[slot][row] = make_float2(200.f*t1l[i], __int_as_float(t1c[i]));
    dmp2[slot][row] = make_float2(200.f*t2l[i], __int_as_float(t2c[i]));
  }
  __syncthreads();

  // stage 1: 128 threads, each scans 16 slots of one row -> top-2
  if (tid < 128) {
    int row = tid >> 2, seg = tid & 3;
    float bl0 = -3.0e38f, bl1 = -3.0e38f; int bc0 = 0, bc1 = 0;
#pragma unroll
    for (int s = 0; s < 16; ++s) {
      int sl = seg*16 + s;
#pragma unroll
      for (int q = 0; q < 2; ++q) {
        float2 pr = q ? dmp2[sl][row] : dmp1[sl][row];
        float pl = pr.x; int pc = __float_as_int(pr.y);
        if (pl > bl0 || (pl == bl0 && pc < bc0)) {
          bl1 = bl0; bc1 = bc0; bl0 = pl; bc0 = pc;
        } else if (pl > bl1 || (pl == bl1 && pc < bc1)) {
          bl1 = pl; bc1 = pc;
        }
      }
    }
    d2[row][seg] = make_float4(bl0, __int_as_float(bc0), bl1, __int_as_float(bc1));
  }
  __syncthreads();

  // stage 2: 32 threads merge 4 segments -> chunk top-2 -> part
  if (tid < 32) {
    float bl0 = -3.0e38f, bl1 = -3.0e38f; int bc0 = 0, bc1 = 0;
#pragma unroll
    for (int seg = 0; seg < 4; ++seg) {
      float4 v = d2[tid][seg];
#pragma unroll
      for (int q = 0; q < 2; ++q) {
        float pl = q ? v.z : v.x;
        int   pc = __float_as_int(q ? v.w : v.y);
        if (pl > bl0 || (pl == bl0 && pc < bc0)) {
          bl1 = bl0; bc1 = bc0; bl0 = pl; bc0 = pc;
        } else if (pl > bl1 || (pl == bl1 && pc < bc1)) {
          bl1 = pl; bc1 = pc;
        }
      }
    }
    part[(size_t)blockIdx.y*NROWS + n0 + tid] =
        make_float4(bl0, __int_as_float(bc0), bl1, __int_as_float(bc1));
  }
}

// ---------------------------------------------------------------------------
// combine: per row, 8 approx pairs (top-2 x 4 chunks). Exact fp32 recompute of
// all candidates within MARGIN of the approx max -> exact argmin/idx. Softmax
// stats for the loss from the approx pairs (threshold 327.68 -> approx fine).
// ---------------------------------------------------------------------------
__global__ __launch_bounds__(256) void combine_kernel(const float* __restrict__ z,
                                                      const float* __restrict__ emb,
                                                      float* __restrict__ ws,
                                                      float* __restrict__ out) {
  const float4* part = (const float4*)(ws + WS_PART);
  int n = blockIdx.x*256 + threadIdx.x;

  float l[8]; int c[8];
#pragma unroll
  for (int ch = 0; ch < KSPLIT; ++ch) {
    float4 v = part[(size_t)ch*NROWS + n];
    l[ch*2+0] = v.x; c[ch*2+0] = __float_as_int(v.y);
    l[ch*2+1] = v.z; c[ch*2+1] = __float_as_int(v.w);
  }
  float mm = l[0];
#pragma unroll
  for (int i = 1; i < 8; ++i) mm = fmaxf(mm, l[i]);

  // exact recompute of candidates (z reads lane-coalesced: consecutive hw)
  int bb = n >> 8, hw = n & 255;
  float zr[32];
  float zn = 0.f;
#pragma unroll
  for (int cc = 0; cc < CDIM; ++cc) {
    zr[cc] = z[(size_t)bb*8192 + cc*256 + hw];
    zn = fmaf(zr[cc], zr[cc], zn);
  }
  float bd = 3.0e38f; int bc = 0x7fffffff;
#pragma unroll
  for (int i = 0; i < 8; ++i) {
    if (l[i] > mm - MARGIN) {
      int code = c[i];
      const float* er = emb + (size_t)code*CDIM;
      float dot = 0.f;
#pragma unroll
      for (int cc = 0; cc < CDIM; ++cc) dot = fmaf(zr[cc], er[cc], dot);
      float d = (zn + ws[WS_ENORM + code]) - 2.f*dot;   // exact fp32 distance
      if (d < bd || (d == bd && code < bc)) { bd = d; bc = code; }
    }
  }
  out[OUT_IDX + n] = (float)bc;

  // loss softmax from approx pairs (max term gives exp(0)=1 -> NaN-proof)
  float s = 0.f;
#pragma unroll
  for (int i = 0; i < 8; ++i) s += __expf(l[i] - mm);
  float lse = mm + __logf(s);

  float plp = 0.f;
#pragma unroll
  for (int i = 0; i < 8; ++i) {
    float u = l[i] - lse;
    float p = __expf(u);
    plp = fmaf(p, u, plp);
    if (p > 1e-12f) atomicAdd(&ws[WS_AVGP + c[i]], p);
  }
  for (int off = 1; off < 64; off <<= 1) plp += __shfl_xor(plp, off);
  if ((threadIdx.x & 63) == 0) atomicAdd(&ws[WS_PLP], plp);
}

// ---------------------------------------------------------------------------
// zq epilogue: straight-through output + MSE (exact)
// ---------------------------------------------------------------------------
__global__ __launch_bounds__(256) void zq_kernel(const float* __restrict__ z,
                                                 const float* __restrict__ emb,
                                                 float* __restrict__ ws,
                                                 float* __restrict__ out) {
  int f  = blockIdx.x*256 + threadIdx.x;   // f = b*8192 + c*256 + hw
  int hw = f & 255;
  int c  = (f >> 8) & 31;
  int b  = f >> 13;
  int n  = b*256 + hw;
  int idx = (int)out[OUT_IDX + n];
  float zq = emb[(size_t)idx*CDIM + c];
  float zf = z[f];
  out[f] = zf + (zq - zf);
  float d = zq - zf;
  float msel = d*d;
  for (int off = 1; off < 64; off <<= 1) msel += __shfl_xor(msel, off);
  if ((threadIdx.x & 63) == 0) atomicAdd(&ws[WS_MSE], msel);
}

__global__ __launch_bounds__(256) void finalize_kernel(const float* __restrict__ ws,
                                                       float* __restrict__ out) {
  __shared__ float red[256];
  float h = 0.f;
  for (int k = threadIdx.x; k < KCODES; k += 256) {
    float ap = ws[WS_AVGP + k] * (1.f/8192.f);
    h += ap * __logf(ap + 1e-5f);
  }
  red[threadIdx.x] = h;
  __syncthreads();
  for (int st = 128; st > 0; st >>= 1) {
    if (threadIdx.x < st) red[threadIdx.x] += red[threadIdx.x + st];
    __syncthreads();
  }
  if (threadIdx.x == 0) {
    float mse        = ws[WS_MSE] * (1.f/(8192.f*32.f));
    float sample_ent = -ws[WS_PLP] * (1.f/8192.f);
    out[OUT_LOSS] = 1.25f*mse + 0.1f*(sample_ent + red[0]);
  }
}

extern "C" void kernel_launch(void* const* d_in, const int* in_sizes, int n_in,
                              void* d_out, int out_size, void* d_ws, size_t ws_size,
                              hipStream_t stream) {
  (void)in_sizes; (void)n_in; (void)out_size; (void)ws_size;
  const float* z   = (const float*)d_in[0];
  const float* emb = (const float*)d_in[1];
  float* out = (float*)d_out;
  float* ws  = (float*)d_ws;

  // zero scalar accumulators + avg_probs
  hipMemsetAsync(ws, 0, (size_t)(16 + KCODES)*sizeof(float), stream);

  prep_e         <<<KCODES/256, 256, 0, stream>>>(emb, ws);
  prep_z         <<<NROWS/256, 256, 0, stream>>>(z, ws);
  gemm_pass      <<<dim3(NROWS/32, KSPLIT), 256, 0, stream>>>(ws, ws);
  combine_kernel <<<NROWS/256, 256, 0, stream>>>(z, emb, ws, out);
  zq_kernel      <<<(NROWS*CDIM)/256, 256, 0, stream>>>(z, emb, ws, out);
  finalize_kernel<<<1, 256, 0, stream>>>(ws, out);
}

// Round 11
// 132.721 us; speedup vs baseline: 5.0171x; 1.5465x over previous
//
#include <hip/hip_runtime.h>

#define KCODES 16384
#define CDIM   32
#define NROWS  8192
#define KSPLIT 4                  // chunks (blockIdx.y)
#define CHUNK  (KCODES/KSPLIT)    // 4096
#define WCODES 1024               // codes per wave
#define NT     (WCODES/16)        // 64 MFMA code-tiles per wave
#define MARGIN 2.5f               // >3x worst-case f16 logit error (~0.8) + tag noise

typedef _Float16 half8 __attribute__((ext_vector_type(8)));
typedef float    floatx4 __attribute__((ext_vector_type(4)));

// workspace layout (float indices)
#define WS_MSE   0
#define WS_PLP   1
#define WS_AVGP  16                      // [16384]
#define WS_ENORM (16 + KCODES)           // [16384] fp32, exact
#define WS_ZNORM (16 + 2*KCODES)         // [8192]  fp32
#define WS_PART  (16 + 2*KCODES + NROWS) // float4[KSPLIT][NROWS]
#define WS_E16   (WS_PART + 4*KSPLIT*NROWS)      // f16[16384][32]
#define WS_Z16   (WS_E16 + KCODES*16)            // f16[8192][32]

// output layout (floats): z_q [0, N*C), loss [N*C], idx [N*C+1, ...)
#define OUT_LOSS (NROWS*CDIM)
#define OUT_IDX  (NROWS*CDIM + 1)

// ---------------------------------------------------------------------------
// prep: blocks [0,64): e-rows (enorm exact + f16 convert + zero avg_probs);
//       blocks [64,96): z-rows (znorm + f16 convert); block 64 zeroes scalars.
// ---------------------------------------------------------------------------
__global__ __launch_bounds__(256) void prep_kernel(const float* __restrict__ z,
                                                   const float* __restrict__ emb,
                                                   float* __restrict__ ws) {
  const int tid = threadIdx.x;
  if (blockIdx.x < 64) {
    int k = blockIdx.x * 256 + tid;
    const float4* p = (const float4*)(emb + (size_t)k * CDIM);
    _Float16* e16 = (_Float16*)(ws + WS_E16);
    float s = 0.f;
    half8 h[4];
#pragma unroll
    for (int i = 0; i < 8; ++i) {
      float4 v = p[i];
      s += v.x*v.x + v.y*v.y + v.z*v.z + v.w*v.w;
      h[i>>1][(i&1)*4+0] = (_Float16)v.x;
      h[i>>1][(i&1)*4+1] = (_Float16)v.y;
      h[i>>1][(i&1)*4+2] = (_Float16)v.z;
      h[i>>1][(i&1)*4+3] = (_Float16)v.w;
    }
    ws[WS_ENORM + k] = s;
    ws[WS_AVGP + k]  = 0.f;
    half8* dst = (half8*)(e16 + (size_t)k*32);
#pragma unroll
    for (int i = 0; i < 4; ++i) dst[i] = h[i];
  } else {
    int b = blockIdx.x - 64;
    int n = b*256 + tid;
    if (b == 0 && tid < 16) ws[tid] = 0.f;
    _Float16* z16 = (_Float16*)(ws + WS_Z16);
    float s = 0.f;
    half8 h[4];
#pragma unroll
    for (int c = 0; c < CDIM; ++c) {
      float v = z[(size_t)b*8192 + c*256 + tid];
      s = fmaf(v, v, s);
      h[c>>3][c&7] = (_Float16)v;
    }
    ws[WS_ZNORM + n] = s;
    half8* dst = (half8*)(z16 + (size_t)n*32);
#pragma unroll
    for (int i = 0; i < 4; ++i) dst[i] = h[i];
  }
}

// ---------------------------------------------------------------------------
// gemm_pass: block = (32 rows, chunk); 4 waves x 1024 codes; per wave 2 row-
// tiles x 64 tiles of v_mfma_f32_16x16x32_f16 (K=32 = CDIM). The -(zn+en)/2
// bias rides in the MFMA C operand, so D = lp directly. Per-lane top-2 via
// CODE-TAGGED floats: low 6 mantissa bits hold (63-t) -> insert is just
// and/or/med3/max (4 VALU/elem, no index registers, no cndmask chains).
// Tag noise <= ~0.006 l-units; idx exactness restored in combine by fp32
// recompute of all candidates within MARGIN. R10: VALUBusy 91% / Mfma 5%
// with ~10 VALU/elem -> this halves the hot-loop VALU.
// ---------------------------------------------------------------------------
__global__ __launch_bounds__(256) void gemm_pass(const float* __restrict__ ws_ro,
                                                 float* __restrict__ ws) {
  __shared__ float2 dmp1[64][33];
  __shared__ float2 dmp2[64][33];
  __shared__ float4 d2[32][4];

  const int tid  = threadIdx.x;
  const int wv   = tid >> 6;
  const int lane = tid & 63;
  const int nn   = lane & 15;
  const int quad = lane >> 4;
  const int n0   = blockIdx.x * 32;
  const int kb   = blockIdx.y * CHUNK + wv * WCODES;

  const half8* z16v = (const half8*)(ws_ro + WS_Z16);
  const half8* e16v = (const half8*)(ws_ro + WS_E16);
  const float* enorm = ws_ro + WS_ENORM;
  const float* znorm = ws_ro + WS_ZNORM;
  float4* part = (float4*)(ws + WS_PART);

  half8 a0 = z16v[(size_t)(n0 + nn)*4 + quad];
  half8 a1 = z16v[(size_t)(n0 + 16 + nn)*4 + quad];

  float nzn2[8];                        // -0.5*znorm[row]
#pragma unroll
  for (int i = 0; i < 8; ++i)
    nzn2[i] = -0.5f * znorm[n0 + (i>>2)*16 + quad*4 + (i&3)];

  float t1l[8], t2l[8];
#pragma unroll
  for (int i = 0; i < 8; ++i) { t1l[i] = -3.0e38f; t2l[i] = -3.0e38f; }

  half8 bcur = e16v[(size_t)(kb + nn)*4 + quad];
  float en2c = 0.5f * enorm[kb + nn];

  for (int t = 0; t < NT; ++t) {
    const int tn = (t + 1 < NT) ? t + 1 : t;      // clamp: last prefetch reuses
    half8 bn   = e16v[(size_t)(kb + tn*16 + nn)*4 + quad];
    float en2n = 0.5f * enorm[kb + tn*16 + nn];

    floatx4 c0, c1;
#pragma unroll
    for (int i = 0; i < 4; ++i) { c0[i] = nzn2[i] - en2c; c1[i] = nzn2[i+4] - en2c; }

    floatx4 d0 = __builtin_amdgcn_mfma_f32_16x16x32_f16(a0, bcur, c0, 0, 0, 0);
    floatx4 d1 = __builtin_amdgcn_mfma_f32_16x16x32_f16(a1, bcur, c1, 0, 0, 0);

    const int tag = 63 - t;                       // bigger tag = smaller code
#pragma unroll
    for (int i = 0; i < 8; ++i) {
      float lp = (i < 4) ? d0[i & 3] : d1[i & 3];
      float v  = __int_as_float((__float_as_int(lp) & 0xFFFFFFC0) | tag);
      t2l[i] = __builtin_amdgcn_fmed3f(v, t1l[i], t2l[i]);
      t1l[i] = fmaxf(t1l[i], v);
    }
    bcur = bn; en2c = en2n;
  }

  // dump per-(lane,row) top-2: unpack tag -> code, scale to true logits l=200*lp
  const int slot = wv*16 + nn;
#pragma unroll
  for (int i = 0; i < 8; ++i) {
    int row = (i>>2)*16 + quad*4 + (i&3);
    int c1i = kb + nn + 16*(63 - (__float_as_int(t1l[i]) & 63));
    int c2i = kb + nn + 16*(63 - (__float_as_int(t2l[i]) & 63));
    dmp1[slot][row] = make_float2(200.f*t1l[i], __int_as_float(c1i));
    dmp2[slot][row] = make_float2(200.f*t2l[i], __int_as_float(c2i));
  }
  __syncthreads();

  // stage 1: 128 threads, each scans 16 slots of one row -> top-2
  if (tid < 128) {
    int row = tid >> 2, seg = tid & 3;
    float bl0 = -3.0e38f, bl1 = -3.0e38f; int bc0 = 0, bc1 = 0;
#pragma unroll
    for (int s = 0; s < 16; ++s) {
      int sl = seg*16 + s;
#pragma unroll
      for (int q = 0; q < 2; ++q) {
        float2 pr = q ? dmp2[sl][row] : dmp1[sl][row];
        float pl = pr.x; int pc = __float_as_int(pr.y);
        if (pl > bl0 || (pl == bl0 && pc < bc0)) {
          bl1 = bl0; bc1 = bc0; bl0 = pl; bc0 = pc;
        } else if (pl > bl1 || (pl == bl1 && pc < bc1)) {
          bl1 = pl; bc1 = pc;
        }
      }
    }
    d2[row][seg] = make_float4(bl0, __int_as_float(bc0), bl1, __int_as_float(bc1));
  }
  __syncthreads();

  // stage 2: 32 threads merge 4 segments -> chunk top-2 -> part
  if (tid < 32) {
    float bl0 = -3.0e38f, bl1 = -3.0e38f; int bc0 = 0, bc1 = 0;
#pragma unroll
    for (int seg = 0; seg < 4; ++seg) {
      float4 v = d2[tid][seg];
#pragma unroll
      for (int q = 0; q < 2; ++q) {
        float pl = q ? v.z : v.x;
        int   pc = __float_as_int(q ? v.w : v.y);
        if (pl > bl0 || (pl == bl0 && pc < bc0)) {
          bl1 = bl0; bc1 = bc0; bl0 = pl; bc0 = pc;
        } else if (pl > bl1 || (pl == bl1 && pc < bc1)) {
          bl1 = pl; bc1 = pc;
        }
      }
    }
    part[(size_t)blockIdx.y*NROWS + n0 + tid] =
        make_float4(bl0, __int_as_float(bc0), bl1, __int_as_float(bc1));
  }
}

// ---------------------------------------------------------------------------
// combine (+fused zq): per row, 8 approx pairs -> exact fp32 recompute of all
// candidates within MARGIN -> exact idx; z_q straight-through write + MSE
// (reuses the exact z row already in registers); loss softmax from the pairs.
// ---------------------------------------------------------------------------
__global__ __launch_bounds__(256) void combine_kernel(const float* __restrict__ z,
                                                      const float* __restrict__ emb,
                                                      float* __restrict__ ws,
                                                      float* __restrict__ out) {
  const float4* part = (const float4*)(ws + WS_PART);
  int n = blockIdx.x*256 + threadIdx.x;

  float l[8]; int c[8];
#pragma unroll
  for (int ch = 0; ch < KSPLIT; ++ch) {
    float4 v = part[(size_t)ch*NROWS + n];
    l[ch*2+0] = v.x; c[ch*2+0] = __float_as_int(v.y);
    l[ch*2+1] = v.z; c[ch*2+1] = __float_as_int(v.w);
  }
  float mm = l[0];
#pragma unroll
  for (int i = 1; i < 8; ++i) mm = fmaxf(mm, l[i]);

  int bb = n >> 8, hw = n & 255;
  float zr[32];
  float zn = 0.f;
#pragma unroll
  for (int cc = 0; cc < CDIM; ++cc) {
    zr[cc] = z[(size_t)bb*8192 + cc*256 + hw];
    zn = fmaf(zr[cc], zr[cc], zn);
  }
  float bd = 3.0e38f; int bc = 0x7fffffff;
#pragma unroll
  for (int i = 0; i < 8; ++i) {
    if (l[i] > mm - MARGIN) {
      int code = c[i];
      const float* er = emb + (size_t)code*CDIM;
      float dot = 0.f;
#pragma unroll
      for (int cc = 0; cc < CDIM; ++cc) dot = fmaf(zr[cc], er[cc], dot);
      float d = (zn + ws[WS_ENORM + code]) - 2.f*dot;   // exact fp32 distance
      if (d < bd || (d == bd && code < bc)) { bd = d; bc = code; }
    }
  }
  out[OUT_IDX + n] = (float)bc;

  // fused zq: straight-through output + MSE (coalesced per-c stores)
  const float* er = emb + (size_t)bc*CDIM;
  float msel = 0.f;
#pragma unroll
  for (int cc = 0; cc < CDIM; ++cc) {
    float zq = er[cc];
    float df = zq - zr[cc];
    msel = fmaf(df, df, msel);
    out[(size_t)bb*8192 + cc*256 + hw] = zr[cc] + (zq - zr[cc]);
  }
  for (int off = 1; off < 64; off <<= 1) msel += __shfl_xor(msel, off);
  if ((threadIdx.x & 63) == 0) atomicAdd(&ws[WS_MSE], msel);

  // loss softmax from approx pairs (max term = exp(0)=1 -> NaN-proof)
  float s = 0.f;
#pragma unroll
  for (int i = 0; i < 8; ++i) s += __expf(l[i] - mm);
  float lse = mm + __logf(s);

  float plp = 0.f;
#pragma unroll
  for (int i = 0; i < 8; ++i) {
    float u = l[i] - lse;
    float p = __expf(u);
    plp = fmaf(p, u, plp);
    if (p > 1e-12f) atomicAdd(&ws[WS_AVGP + c[i]], p);
  }
  for (int off = 1; off < 64; off <<= 1) plp += __shfl_xor(plp, off);
  if ((threadIdx.x & 63) == 0) atomicAdd(&ws[WS_PLP], plp);
}

__global__ __launch_bounds__(256) void finalize_kernel(const float* __restrict__ ws,
                                                       float* __restrict__ out) {
  __shared__ float red[256];
  float h = 0.f;
  for (int k = threadIdx.x; k < KCODES; k += 256) {
    float ap = ws[WS_AVGP + k] * (1.f/8192.f);
    h += ap * __logf(ap + 1e-5f);
  }
  red[threadIdx.x] = h;
  __syncthreads();
  for (int st = 128; st > 0; st >>= 1) {
    if (threadIdx.x < st) red[threadIdx.x] += red[threadIdx.x + st];
    __syncthreads();
  }
  if (threadIdx.x == 0) {
    float mse        = ws[WS_MSE] * (1.f/(8192.f*32.f));
    float sample_ent = -ws[WS_PLP] * (1.f/8192.f);
    out[OUT_LOSS] = 1.25f*mse + 0.1f*(sample_ent + red[0]);
  }
}

extern "C" void kernel_launch(void* const* d_in, const int* in_sizes, int n_in,
                              void* d_out, int out_size, void* d_ws, size_t ws_size,
                              hipStream_t stream) {
  (void)in_sizes; (void)n_in; (void)out_size; (void)ws_size;
  const float* z   = (const float*)d_in[0];
  const float* emb = (const float*)d_in[1];
  float* out = (float*)d_out;
  float* ws  = (float*)d_ws;

  prep_kernel    <<<96, 256, 0, stream>>>(z, emb, ws);
  gemm_pass      <<<dim3(NROWS/32, KSPLIT), 256, 0, stream>>>(ws, ws);
  combine_kernel <<<NROWS/256, 256, 0, stream>>>(z, emb, ws, out);
  finalize_kernel<<<1, 256, 0, stream>>>(ws, out);
}

// Round 12
// 131.935 us; speedup vs baseline: 5.0470x; 1.0060x over previous
//
#include <hip/hip_runtime.h>

#define KCODES 16384
#define CDIM   32
#define NROWS  8192
#define KSPLIT 8                  // chunks (blockIdx.y)
#define CHUNK  (KCODES/KSPLIT)    // 2048
#define WCODES (CHUNK/4)          // 512 codes per wave
#define NT     (WCODES/16)        // 32 MFMA code-tiles per wave
#define MARGIN 4.0f               // covers f16 mfma error (~0.8) + 2x tag noise (0.4)

typedef _Float16 half8 __attribute__((ext_vector_type(8)));
typedef float    floatx4 __attribute__((ext_vector_type(4)));

// workspace layout (float indices) — total ~2.79 MB (< R4-proven 3.57 MB)
#define WS_MSE   0
#define WS_PLP   1
#define WS_AVGP  16                      // [16384]
#define WS_ENORM (16 + KCODES)           // [16384] fp32, exact
#define WS_ZNORM (16 + 2*KCODES)         // [8192]  fp32
#define WS_PART  (16 + 2*KCODES + NROWS) // float4[KSPLIT][NROWS]
#define WS_E16   (WS_PART + 4*KSPLIT*NROWS)      // f16[16384][32]
#define WS_Z16   (WS_E16 + KCODES*16)            // f16[8192][32]

// output layout (floats): z_q [0, N*C), loss [N*C], idx [N*C+1, ...)
#define OUT_LOSS (NROWS*CDIM)
#define OUT_IDX  (NROWS*CDIM + 1)

// ---------------------------------------------------------------------------
// prep: blocks [0,64): e-rows (enorm exact + f16 convert + zero avg_probs);
//       blocks [64,96): z-rows (znorm + f16 convert); block 64 zeroes scalars.
// ---------------------------------------------------------------------------
__global__ __launch_bounds__(256) void prep_kernel(const float* __restrict__ z,
                                                   const float* __restrict__ emb,
                                                   float* __restrict__ ws) {
  const int tid = threadIdx.x;
  if (blockIdx.x < 64) {
    int k = blockIdx.x * 256 + tid;
    const float4* p = (const float4*)(emb + (size_t)k * CDIM);
    _Float16* e16 = (_Float16*)(ws + WS_E16);
    float s = 0.f;
    half8 h[4];
#pragma unroll
    for (int i = 0; i < 8; ++i) {
      float4 v = p[i];
      s += v.x*v.x + v.y*v.y + v.z*v.z + v.w*v.w;
      h[i>>1][(i&1)*4+0] = (_Float16)v.x;
      h[i>>1][(i&1)*4+1] = (_Float16)v.y;
      h[i>>1][(i&1)*4+2] = (_Float16)v.z;
      h[i>>1][(i&1)*4+3] = (_Float16)v.w;
    }
    ws[WS_ENORM + k] = s;
    ws[WS_AVGP + k]  = 0.f;
    half8* dst = (half8*)(e16 + (size_t)k*32);
#pragma unroll
    for (int i = 0; i < 4; ++i) dst[i] = h[i];
  } else {
    int b = blockIdx.x - 64;
    int n = b*256 + tid;
    if (b == 0 && tid < 16) ws[tid] = 0.f;
    _Float16* z16 = (_Float16*)(ws + WS_Z16);
    float s = 0.f;
    half8 h[4];
#pragma unroll
    for (int c = 0; c < CDIM; ++c) {
      float v = z[(size_t)b*8192 + c*256 + tid];
      s = fmaf(v, v, s);
      h[c>>3][c&7] = (_Float16)v;
    }
    ws[WS_ZNORM + n] = s;
    half8* dst = (half8*)(z16 + (size_t)n*32);
#pragma unroll
    for (int i = 0; i < 4; ++i) dst[i] = h[i];
  }
}

// ---------------------------------------------------------------------------
// gemm_pass: block = (32 rows, chunk of 2048 codes); 4 waves x 512 codes.
// Per wave: 2 row-tiles x 32 tiles of v_mfma_f32_16x16x32_f16 (K=32=CDIM),
// bias -(zn+en)/2 rides in the C operand -> D = lp directly. Top-2 per
// (lane,row) via 12-bit FULL-CODE-tagged floats (tag = wv*512+16t+nn in the
// low mantissa bits -> candidates are single floats). Cross-lane reduction:
// 4-step shfl_xor butterfly over the 16 nn-lanes (min+3max merge) -> LDS is
// 1 KB (R11's 35.8 KB dump capped residency at 2.3 blocks/CU). KSPLIT=8 ->
// 2048 blocks = 8 blocks/CU; VGPR ~52 -> target near-full occupancy.
// ---------------------------------------------------------------------------
__global__ __launch_bounds__(256) void gemm_pass(const float* __restrict__ ws_ro,
                                                 float* __restrict__ ws) {
  __shared__ float2 wdump[4][32];       // [wave][row] top-2 tagged floats

  const int tid  = threadIdx.x;
  const int wv   = tid >> 6;
  const int lane = tid & 63;
  const int nn   = lane & 15;
  const int quad = lane >> 4;
  const int n0   = blockIdx.x * 32;
  const int kb   = blockIdx.y * CHUNK + wv * WCODES;

  const half8* z16v = (const half8*)(ws_ro + WS_Z16);
  const half8* e16v = (const half8*)(ws_ro + WS_E16);
  const float* enorm = ws_ro + WS_ENORM;
  const float* znorm = ws_ro + WS_ZNORM;
  float4* part = (float4*)(ws + WS_PART);

  half8 a0 = z16v[(size_t)(n0 + nn)*4 + quad];
  half8 a1 = z16v[(size_t)(n0 + 16 + nn)*4 + quad];

  float nzn2[8];                        // -0.5*znorm[row]
#pragma unroll
  for (int i = 0; i < 8; ++i)
    nzn2[i] = -0.5f * znorm[n0 + (i>>2)*16 + quad*4 + (i&3)];

  float t1l[8], t2l[8];
#pragma unroll
  for (int i = 0; i < 8; ++i) { t1l[i] = -3.0e38f; t2l[i] = -3.0e38f; }

  const int tagbase = wv*WCODES + nn;   // full within-chunk code of tile 0
  half8 bcur = e16v[(size_t)(kb + nn)*4 + quad];
  float en2c = 0.5f * enorm[kb + nn];

  for (int t = 0; t < NT; ++t) {
    const int tn = (t + 1 < NT) ? t + 1 : t;      // clamp: last prefetch reuses
    half8 bn   = e16v[(size_t)(kb + tn*16 + nn)*4 + quad];
    float en2n = 0.5f * enorm[kb + tn*16 + nn];

    floatx4 c0, c1;
#pragma unroll
    for (int i = 0; i < 4; ++i) { c0[i] = nzn2[i] - en2c; c1[i] = nzn2[i+4] - en2c; }

    floatx4 d0 = __builtin_amdgcn_mfma_f32_16x16x32_f16(a0, bcur, c0, 0, 0, 0);
    floatx4 d1 = __builtin_amdgcn_mfma_f32_16x16x32_f16(a1, bcur, c1, 0, 0, 0);

    const int tg = tagbase + 16*t;                // 12-bit within-chunk code
#pragma unroll
    for (int i = 0; i < 8; ++i) {
      float lp = (i < 4) ? d0[i & 3] : d1[i & 3];
      float v  = __int_as_float((__float_as_int(lp) & 0xFFFFF000) | tg);  // bfi
      t2l[i] = __builtin_amdgcn_fmed3f(v, t1l[i], t2l[i]);
      t1l[i] = fmaxf(t1l[i], v);
    }
    bcur = bn; en2c = en2n;
  }

  // butterfly top-2 merge across the 16 nn-lanes (xor 1,2,4,8 stay in-group)
#pragma unroll
  for (int i = 0; i < 8; ++i) {
    float v1 = t1l[i], v2 = t2l[i];
#pragma unroll
    for (int m = 1; m < 16; m <<= 1) {
      float o1 = __shfl_xor(v1, m);
      float o2 = __shfl_xor(v2, m);
      float mn = fminf(v1, o1);
      v1 = fmaxf(v1, o1);
      v2 = fmaxf(mn, fmaxf(v2, o2));
    }
    if (nn == 0) wdump[wv][(i>>2)*16 + quad*4 + (i&3)] = make_float2(v1, v2);
  }
  __syncthreads();

  // merge 4 waves per row, unpack tags -> (l, code), write part
  if (tid < 32) {
    float v1 = -3.0e38f, v2 = -3.0e38f;
#pragma unroll
    for (int w = 0; w < 4; ++w) {
      float2 p = wdump[w][tid];
      float mn = fminf(v1, p.x);
      v1 = fmaxf(v1, p.x);
      v2 = fmaxf(mn, fmaxf(v2, p.y));
    }
    int b1 = __float_as_int(v1), b2 = __float_as_int(v2);
    int c1i = blockIdx.y*CHUNK + (b1 & 0xFFF);
    int c2i = blockIdx.y*CHUNK + (b2 & 0xFFF);
    float l1 = 200.f * __int_as_float(b1 & 0xFFFFF000);
    float l2 = 200.f * __int_as_float(b2 & 0xFFFFF000);
    part[(size_t)blockIdx.y*NROWS + n0 + tid] =
        make_float4(l1, __int_as_float(c1i), l2, __int_as_float(c2i));
  }
}

// ---------------------------------------------------------------------------
// combine (+fused zq): per row, 16 approx pairs (top-2 x 8 chunks) -> exact
// fp32 recompute of all candidates within MARGIN -> exact idx; z_q straight-
// through write + MSE; loss softmax from the approx pairs (NaN-proof: max
// term contributes exp(0)=1). 128 blocks x 64 threads spreads the latency.
// ---------------------------------------------------------------------------
__global__ __launch_bounds__(64) void combine_kernel(const float* __restrict__ z,
                                                     const float* __restrict__ emb,
                                                     float* __restrict__ ws,
                                                     float* __restrict__ out) {
  const float4* part = (const float4*)(ws + WS_PART);
  int n = blockIdx.x*64 + threadIdx.x;

  float l[16]; int c[16];
#pragma unroll
  for (int ch = 0; ch < KSPLIT; ++ch) {
    float4 v = part[(size_t)ch*NROWS + n];
    l[ch*2+0] = v.x; c[ch*2+0] = __float_as_int(v.y);
    l[ch*2+1] = v.z; c[ch*2+1] = __float_as_int(v.w);
  }
  float mm = l[0];
#pragma unroll
  for (int i = 1; i < 16; ++i) mm = fmaxf(mm, l[i]);

  int bb = n >> 8, hw = n & 255;
  float zr[32];
  float zn = 0.f;
#pragma unroll
  for (int cc = 0; cc < CDIM; ++cc) {
    zr[cc] = z[(size_t)bb*8192 + cc*256 + hw];
    zn = fmaf(zr[cc], zr[cc], zn);
  }
  float bd = 3.0e38f; int bc = 0x7fffffff;
#pragma unroll
  for (int i = 0; i < 16; ++i) {
    if (l[i] > mm - MARGIN) {
      int code = c[i];
      const float4* er4 = (const float4*)(emb + (size_t)code*CDIM);
      float dot = 0.f;
#pragma unroll
      for (int q = 0; q < 8; ++q) {
        float4 e4 = er4[q];
        dot = fmaf(zr[q*4+0], e4.x, dot);
        dot = fmaf(zr[q*4+1], e4.y, dot);
        dot = fmaf(zr[q*4+2], e4.z, dot);
        dot = fmaf(zr[q*4+3], e4.w, dot);
      }
      float d = (zn + ws[WS_ENORM + code]) - 2.f*dot;   // exact fp32 distance
      if (d < bd || (d == bd && code < bc)) { bd = d; bc = code; }
    }
  }
  out[OUT_IDX + n] = (float)bc;

  // fused zq: straight-through output + MSE (coalesced per-c stores)
  const float* er = emb + (size_t)bc*CDIM;
  float msel = 0.f;
#pragma unroll
  for (int cc = 0; cc < CDIM; ++cc) {
    float zq = er[cc];
    float df = zq - zr[cc];
    msel = fmaf(df, df, msel);
    out[(size_t)bb*8192 + cc*256 + hw] = zr[cc] + (zq - zr[cc]);
  }
  for (int off = 1; off < 64; off <<= 1) msel += __shfl_xor(msel, off);
  if (threadIdx.x == 0) atomicAdd(&ws[WS_MSE], msel);

  // loss softmax from approx pairs
  float s = 0.f;
#pragma unroll
  for (int i = 0; i < 16; ++i) s += __expf(l[i] - mm);
  float lse = mm + __logf(s);

  float plp = 0.f;
#pragma unroll
  for (int i = 0; i < 16; ++i) {
    float u = l[i] - lse;
    float p = __expf(u);
    plp = fmaf(p, u, plp);
    if (p > 1e-12f) atomicAdd(&ws[WS_AVGP + c[i]], p);
  }
  for (int off = 1; off < 64; off <<= 1) plp += __shfl_xor(plp, off);
  if (threadIdx.x == 0) atomicAdd(&ws[WS_PLP], plp);
}

__global__ __launch_bounds__(256) void finalize_kernel(const float* __restrict__ ws,
                                                       float* __restrict__ out) {
  __shared__ float red[256];
  float h = 0.f;
  for (int k = threadIdx.x; k < KCODES; k += 256) {
    float ap = ws[WS_AVGP + k] * (1.f/8192.f);
    h += ap * __logf(ap + 1e-5f);
  }
  red[threadIdx.x] = h;
  __syncthreads();
  for (int st = 128; st > 0; st >>= 1) {
    if (threadIdx.x < st) red[threadIdx.x] += red[threadIdx.x + st];
    __syncthreads();
  }
  if (threadIdx.x == 0) {
    float mse        = ws[WS_MSE] * (1.f/(8192.f*32.f));
    float sample_ent = -ws[WS_PLP] * (1.f/8192.f);
    out[OUT_LOSS] = 1.25f*mse + 0.1f*(sample_ent + red[0]);
  }
}

extern "C" void kernel_launch(void* const* d_in, const int* in_sizes, int n_in,
                              void* d_out, int out_size, void* d_ws, size_t ws_size,
                              hipStream_t stream) {
  (void)in_sizes; (void)n_in; (void)out_size; (void)ws_size;
  const float* z   = (const float*)d_in[0];
  const float* emb = (const float*)d_in[1];
  float* out = (float*)d_out;
  float* ws  = (float*)d_ws;

  prep_kernel    <<<96, 256, 0, stream>>>(z, emb, ws);
  gemm_pass      <<<dim3(NROWS/32, KSPLIT), 256, 0, stream>>>(ws, ws);
  combine_kernel <<<NROWS/64, 64, 0, stream>>>(z, emb, ws, out);
  finalize_kernel<<<1, 256, 0, stream>>>(ws, out);
}